// Round 3
// baseline (157.741 us; speedup 1.0000x reference)
//
#include <hip/hip_runtime.h>
#include <cstdint>

#define LL 2048
#define HH 16
#define DD 64
#define NC 32
#define LSTR 1024
#define EPSF 1e-6f
#define PAD 72   // bf16 elements per LDS row

typedef __bf16 bf16x8 __attribute__((ext_vector_type(8)));
typedef float floatx4 __attribute__((ext_vector_type(4)));
typedef unsigned short ushortx8 __attribute__((ext_vector_type(8)));
typedef unsigned short ushortx4 __attribute__((ext_vector_type(4)));
typedef unsigned short ushortx2 __attribute__((ext_vector_type(2)));

static __device__ __forceinline__ float fmap(float x){ return x > 0.f ? x + 1.f : __expf(x); }
static __device__ __forceinline__ unsigned short f2bf(float f){
    unsigned u = __builtin_bit_cast(unsigned, f);
    u += 0x7fffu + ((u >> 16) & 1u);
    return (unsigned short)(u >> 16);
}
static __device__ __forceinline__ float bf2f(unsigned short s){
    unsigned u = ((unsigned)s) << 16;
    return __builtin_bit_cast(float, u);
}
static __device__ __forceinline__ bf16x8 ldf(const unsigned short* p){
    return __builtin_bit_cast(bf16x8, *(const ushortx8*)p);
}

// ---------------- k1: per-chunk KVt[m][d] (bf16) + Ksum (fp32) ----------------
__global__ __launch_bounds__(256) void k1(const float* __restrict__ kp, const float* __restrict__ vp,
                                          unsigned short* __restrict__ kvt, float* __restrict__ ks)
{
    __shared__ __align__(16) unsigned short kft[DD*PAD]; // kf^T: [d][s]
    __shared__ __align__(16) unsigned short v_s[DD*PAD]; // v row-major: [s][m]
    const int ci = blockIdx.x;
    const int c = ci & 31, bh = ci >> 5, b = bh >> 4, h = bh & 15;
    const int t = threadIdx.x;
    const int64_t gbase = ((int64_t)(b*LL + c*DD)*HH + h)*DD;
#pragma unroll
    for (int i = 0; i < 2; ++i) {
        int flat = t + 256*i;                   // 512 pairs: 2 rows x 4 cols each
        int l0 = (flat >> 4) * 2, col = (flat & 15) << 2;
        const float* g0 = kp + gbase + (int64_t)l0*LSTR + col;
        float4 ka = *(const float4*)(g0);
        float4 kb = *(const float4*)(g0 + LSTR);
        unsigned short ua[4] = { f2bf(fmap(ka.x)), f2bf(fmap(ka.y)), f2bf(fmap(ka.z)), f2bf(fmap(ka.w)) };
        unsigned short ub[4] = { f2bf(fmap(kb.x)), f2bf(fmap(kb.y)), f2bf(fmap(kb.z)), f2bf(fmap(kb.w)) };
#pragma unroll
        for (int e = 0; e < 4; ++e)
            *(ushortx2*)(kft + (col+e)*PAD + l0) = ushortx2{ ua[e], ub[e] };
        const float* v0 = vp + gbase + (int64_t)l0*LSTR + col;
        float4 va = *(const float4*)(v0);
        float4 vb = *(const float4*)(v0 + LSTR);
        *(ushortx4*)(v_s + l0*PAD + col)     = ushortx4{ f2bf(va.x), f2bf(va.y), f2bf(va.z), f2bf(va.w) };
        *(ushortx4*)(v_s + (l0+1)*PAD + col) = ushortx4{ f2bf(vb.x), f2bf(vb.y), f2bf(vb.z), f2bf(vb.w) };
    }
    __syncthreads();
    const int w = t >> 6, lane = t & 63, quad = lane >> 4, lr = lane & 15;
    const int m0 = 16*w;
    floatx4 acc[4];
#pragma unroll
    for (int dt = 0; dt < 4; ++dt) acc[dt] = floatx4{0.f,0.f,0.f,0.f};
#pragma unroll
    for (int kk = 0; kk < 2; ++kk) {
        ushortx8 u;
#pragma unroll
        for (int j = 0; j < 8; ++j)
            u[j] = v_s[(kk*32 + quad*8 + j)*PAD + m0 + lr];   // A[m][k=s] = v^T
        bf16x8 a = __builtin_bit_cast(bf16x8, u);
#pragma unroll
        for (int dt = 0; dt < 4; ++dt) {
            bf16x8 bb = ldf(kft + (dt*16+lr)*PAD + kk*32 + quad*8);
            acc[dt] = __builtin_amdgcn_mfma_f32_16x16x32_bf16(a, bb, acc[dt], 0, 0, 0);
        }
    }
    unsigned short* kvo = kvt + (int64_t)ci*4096;   // [m][d] bf16
#pragma unroll
    for (int dt = 0; dt < 4; ++dt)
#pragma unroll
        for (int r = 0; r < 4; ++r)
            kvo[(m0 + quad*4 + r)*DD + dt*16 + lr] = f2bf(acc[dt][r]);
    if (t < DD) {
        float s = 0.f;
#pragma unroll
        for (int j = 0; j < 8; ++j) {
            ushortx8 u = *(const ushortx8*)(kft + t*PAD + j*8);
#pragma unroll
            for (int e = 0; e < 8; ++e) s += bf2f(u[e]);
        }
        ks[(int64_t)ci*DD + t] = s;
    }
}

// ---------------- k2: exclusive prefix over chunks (512 blocks, dword/thread) ----------------
__global__ __launch_bounds__(256) void k2(unsigned short* __restrict__ kvt, float* __restrict__ ks)
{
    const int blk = blockIdx.x;          // 512 = 64 bh * 8 parts
    const int bh = blk >> 3, part = blk & 7, t = threadIdx.x;
    unsigned short* base = kvt + (int64_t)bh*NC*4096 + (part*256 + t)*2;
    float r0 = 0.f, r1 = 0.f;
    unsigned x = *(const unsigned*)base;
    for (int c = 0; c < NC-1; ++c) {
        unsigned xn = *(const unsigned*)(base + (int64_t)(c+1)*4096);
        unsigned o = (unsigned)f2bf(r0) | ((unsigned)f2bf(r1) << 16);
        r0 += bf2f((unsigned short)(x & 0xffffu));
        r1 += bf2f((unsigned short)(x >> 16));
        *(unsigned*)(base + (int64_t)c*4096) = o;
        x = xn;
    }
    *(unsigned*)(base + (int64_t)(NC-1)*4096) = (unsigned)f2bf(r0) | ((unsigned)f2bf(r1) << 16);
    if (part == 0 && t < DD) {
        float r = 0.f;
        float* kb = ks + (int64_t)bh*NC*DD + t;
        for (int c = 0; c < NC; ++c) { float xx = kb[(int64_t)c*DD]; kb[(int64_t)c*DD] = r; r += xx; }
    }
}

// ---------------- k3: per-chunk output via MFMA ----------------
__global__ __launch_bounds__(256) void k3(const float* __restrict__ qp, const float* __restrict__ kp,
                                          const float* __restrict__ vp,
                                          const unsigned short* __restrict__ kvt,
                                          const float* __restrict__ ks, float* __restrict__ outp)
{
    __shared__ __align__(16) unsigned short kfx[80*PAD];  // [s][d]; row64=Kprefix, 65-79=0; scores overlay rows 0-63
    __shared__ __align__(16) unsigned short v_s[DD*PAD];  // v row-major [s][m]
    __shared__ float zr[DD];
    const int ci = blockIdx.x;
    const int c = ci & 31, bh = ci >> 5, b = bh >> 4, h = bh & 15;
    const int t = threadIdx.x;
    const int64_t gbase = ((int64_t)(b*LL + c*DD)*HH + h)*DD;
    const unsigned short* kvg = kvt + (int64_t)ci*4096;
    const float* ksg = ks + (int64_t)ci*DD;
#pragma unroll
    for (int i = 0; i < 4; ++i) {
        int flat = t + 256*i;
        int l = flat >> 4, col = (flat & 15) << 2;
        float4 kq = *(const float4*)(kp + gbase + (int64_t)l*LSTR + col);
        float4 vq = *(const float4*)(vp + gbase + (int64_t)l*LSTR + col);
        *(ushortx4*)(kfx + l*PAD + col) = ushortx4{ f2bf(fmap(kq.x)), f2bf(fmap(kq.y)), f2bf(fmap(kq.z)), f2bf(fmap(kq.w)) };
        *(ushortx4*)(v_s + l*PAD + col) = ushortx4{ f2bf(vq.x), f2bf(vq.y), f2bf(vq.z), f2bf(vq.w) };
    }
    if (t < 135) *(ushortx8*)(kfx + 65*PAD + t*8) = ushortx8{0,0,0,0,0,0,0,0};
    if (t < DD)  kfx[64*PAD + t] = f2bf(ksg[t]);

    const int w = t >> 6, lane = t & 63, quad = lane >> 4, lr = lane & 15;
    const int l0 = 16*w;
    // A-frags of qf straight from global (each wave needs only its own 16 rows)
    bf16x8 aq[2];
#pragma unroll
    for (int kk = 0; kk < 2; ++kk) {
        const float* g = qp + gbase + (int64_t)(l0+lr)*LSTR + kk*32 + quad*8;
        float4 x0 = *(const float4*)(g);
        float4 x1 = *(const float4*)(g + 4);
        ushortx8 u = { f2bf(fmap(x0.x)), f2bf(fmap(x0.y)), f2bf(fmap(x0.z)), f2bf(fmap(x0.w)),
                       f2bf(fmap(x1.x)), f2bf(fmap(x1.y)), f2bf(fmap(x1.z)), f2bf(fmap(x1.w)) };
        aq[kk] = __builtin_bit_cast(bf16x8, u);
    }
    __syncthreads();

    // ---- GEMM1: scores = qf * kf^T, tile 4 = qf . Kprefix ----
    floatx4 sc[5];
#pragma unroll
    for (int tt = 0; tt < 5; ++tt) sc[tt] = floatx4{0.f,0.f,0.f,0.f};
#pragma unroll
    for (int kk = 0; kk < 2; ++kk)
#pragma unroll
        for (int tt = 0; tt < 5; ++tt) {
            bf16x8 bb = ldf(kfx + (tt*16+lr)*PAD + kk*32 + quad*8);
            sc[tt] = __builtin_amdgcn_mfma_f32_16x16x32_bf16(aq[kk], bb, sc[tt], 0, 0, 0);
        }
    __syncthreads();   // all kfx reads done before score overlay

    // ---- causal mask, z row-sums, overlay masked scores on kfx rows 0-63 ----
    float zp[4] = {0.f,0.f,0.f,0.f};
#pragma unroll
    for (int tt = 0; tt < 4; ++tt)
#pragma unroll
        for (int r = 0; r < 4; ++r) {
            int row = l0 + quad*4 + r;
            int col = tt*16 + lr;
            float val = (col <= row) ? sc[tt][r] : 0.f;
            zp[r] += val;
            kfx[row*PAD + col] = f2bf(val);
        }
#pragma unroll
    for (int r = 0; r < 4; ++r) zp[r] += (lr == 0) ? sc[4][r] : 0.f;
#pragma unroll
    for (int m = 1; m < 16; m <<= 1)
#pragma unroll
        for (int r = 0; r < 4; ++r) zp[r] += __shfl_xor(zp[r], m, 64);
    if (lr == 0)
#pragma unroll
        for (int r = 0; r < 4; ++r) zr[l0 + quad*4 + r] = 1.f / (zp[r] + EPSF);
    // no barrier needed: each wave reads back only its own rows (intra-wave dep)

    // ---- GEMM2: out = Amask * v + qf * S   (S-frags direct from global) ----
    floatx4 oa[4];
#pragma unroll
    for (int mt = 0; mt < 4; ++mt) oa[mt] = floatx4{0.f,0.f,0.f,0.f};
#pragma unroll
    for (int kk = 0; kk < 2; ++kk) {
        bf16x8 a2 = ldf(kfx + (l0+lr)*PAD + kk*32 + quad*8);
#pragma unroll
        for (int mt = 0; mt < 4; ++mt) {
            ushortx8 uv;
#pragma unroll
            for (int j = 0; j < 8; ++j)
                uv[j] = v_s[(kk*32 + quad*8 + j)*PAD + mt*16 + lr];   // B[m][k=s] = v^T
            bf16x8 bv = __builtin_bit_cast(bf16x8, uv);
            oa[mt] = __builtin_amdgcn_mfma_f32_16x16x32_bf16(a2, bv, oa[mt], 0, 0, 0);
        }
    }
#pragma unroll
    for (int kk = 0; kk < 2; ++kk)
#pragma unroll
        for (int mt = 0; mt < 4; ++mt) {
            bf16x8 bs = ldf(kvg + (mt*16+lr)*64 + kk*32 + quad*8);    // S^T[m][d] from global
            oa[mt] = __builtin_amdgcn_mfma_f32_16x16x32_bf16(aq[kk], bs, oa[mt], 0, 0, 0);
        }
#pragma unroll
    for (int r = 0; r < 4; ++r) {
        int row = l0 + quad*4 + r;
        float rz = zr[row];
#pragma unroll
        for (int mt = 0; mt < 4; ++mt)
            outp[gbase + (int64_t)row*LSTR + mt*16 + lr] = oa[mt][r] * rz;
    }
}

extern "C" void kernel_launch(void* const* d_in, const int* in_sizes, int n_in,
                              void* d_out, int out_size, void* d_ws, size_t ws_size,
                              hipStream_t stream) {
    const float* q = (const float*)d_in[0];
    const float* k = (const float*)d_in[1];
    const float* v = (const float*)d_in[2];
    float* out = (float*)d_out;
    unsigned short* kvt = (unsigned short*)d_ws;                  // 2048*4096 bf16 = 16 MiB
    float* ks = (float*)((char*)d_ws + (size_t)2048*4096*2);      // 2048*64 fp32 = 512 KiB
    k1<<<2048, 256, 0, stream>>>(k, v, kvt, ks);
    k2<<<512,  256, 0, stream>>>(kvt, ks);
    k3<<<2048, 256, 0, stream>>>(q, k, v, kvt, ks, out);
}

// Round 4
// 156.043 us; speedup vs baseline: 1.0109x; 1.0109x over previous
//
#include <hip/hip_runtime.h>
#include <cstdint>

#define LL 2048
#define HH 16
#define DD 64
#define NC 32
#define LSTR 1024
#define EPSF 1e-6f
#define PAD 72   // bf16 elems per LDS row = 36 dwords -> 2-way (free) on b128 frags

typedef __bf16 bf16x8 __attribute__((ext_vector_type(8)));
typedef float floatx4 __attribute__((ext_vector_type(4)));
typedef unsigned short ushortx8 __attribute__((ext_vector_type(8)));
typedef unsigned short ushortx4 __attribute__((ext_vector_type(4)));
typedef unsigned short ushortx2 __attribute__((ext_vector_type(2)));

static __device__ __forceinline__ float fmap(float x){ return x > 0.f ? x + 1.f : __expf(x); }
static __device__ __forceinline__ unsigned short f2bf(float f){
    unsigned u = __builtin_bit_cast(unsigned, f);
    u += 0x7fffu + ((u >> 16) & 1u);
    return (unsigned short)(u >> 16);
}
static __device__ __forceinline__ float bf2f(unsigned short s){
    unsigned u = ((unsigned)s) << 16;
    return __builtin_bit_cast(float, u);
}
static __device__ __forceinline__ bf16x8 ldf(const unsigned short* p){
    return __builtin_bit_cast(bf16x8, *(const ushortx8*)p);
}

// ---------------- k1: per-chunk KVt[m][d] (bf16) + Ksum (fp32) ----------------
__global__ __launch_bounds__(256) void k1(const float* __restrict__ kp, const float* __restrict__ vp,
                                          unsigned short* __restrict__ kvt, float* __restrict__ ks)
{
    __shared__ __align__(16) unsigned short kft[DD*PAD]; // kf^T [d][s]
    __shared__ __align__(16) unsigned short vtt[DD*PAD]; // v^T  [m][s]
    const int ci = blockIdx.x;
    const int c = ci & 31, bh = ci >> 5, b = bh >> 4, h = bh & 15;
    const int t = threadIdx.x;
    const int64_t gbase = ((int64_t)(b*LL + c*DD)*HH + h)*DD;
#pragma unroll
    for (int i = 0; i < 2; ++i) {
        int flat = t + 256*i;                    // 512 items: 2 rows x 4 cols each
        int l0 = (flat >> 4) * 2, col = (flat & 15) << 2;
        const float* gk = kp + gbase + (int64_t)l0*LSTR + col;
        const float* gv = vp + gbase + (int64_t)l0*LSTR + col;
        float4 ka = *(const float4*)(gk);
        float4 kb = *(const float4*)(gk + LSTR);
        float4 va = *(const float4*)(gv);
        float4 vb = *(const float4*)(gv + LSTR);
        float kaa[4] = {ka.x,ka.y,ka.z,ka.w}, kbb[4] = {kb.x,kb.y,kb.z,kb.w};
        float vaa[4] = {va.x,va.y,va.z,va.w}, vbb[4] = {vb.x,vb.y,vb.z,vb.w};
#pragma unroll
        for (int e = 0; e < 4; ++e) {
            *(ushortx2*)(kft + (col+e)*PAD + l0) = ushortx2{ f2bf(fmap(kaa[e])), f2bf(fmap(kbb[e])) };
            *(ushortx2*)(vtt + (col+e)*PAD + l0) = ushortx2{ f2bf(vaa[e]), f2bf(vbb[e]) };
        }
    }
    __syncthreads();
    const int w = t >> 6, lane = t & 63, quad = lane >> 4, lr = lane & 15;
    const int m0 = 16*w;
    floatx4 acc[4];
#pragma unroll
    for (int dt = 0; dt < 4; ++dt) acc[dt] = floatx4{0.f,0.f,0.f,0.f};
#pragma unroll
    for (int kk = 0; kk < 2; ++kk) {
        bf16x8 a = ldf(vtt + (m0+lr)*PAD + kk*32 + quad*8);
#pragma unroll
        for (int dt = 0; dt < 4; ++dt) {
            bf16x8 bb = ldf(kft + (dt*16+lr)*PAD + kk*32 + quad*8);
            acc[dt] = __builtin_amdgcn_mfma_f32_16x16x32_bf16(a, bb, acc[dt], 0, 0, 0);
        }
    }
    unsigned short* kvo = kvt + (int64_t)ci*4096;   // [m][d]
#pragma unroll
    for (int dt = 0; dt < 4; ++dt)
#pragma unroll
        for (int r = 0; r < 4; ++r)
            kvo[(m0 + quad*4 + r)*DD + dt*16 + lr] = f2bf(acc[dt][r]);
    if (t < DD) {
        float s = 0.f;
#pragma unroll
        for (int j = 0; j < 8; ++j) {
            ushortx8 u = *(const ushortx8*)(kft + t*PAD + j*8);
#pragma unroll
            for (int e = 0; e < 8; ++e) s += bf2f(u[e]);
        }
        ks[(int64_t)ci*DD + t] = s;
    }
}

// ---------------- k2: exclusive prefix over chunks ----------------
__global__ __launch_bounds__(256) void k2(unsigned short* __restrict__ kvt, float* __restrict__ ks)
{
    const int blk = blockIdx.x;          // 512 = 64 bh * 8 parts
    const int bh = blk >> 3, part = blk & 7, t = threadIdx.x;
    unsigned short* base = kvt + (int64_t)bh*NC*4096 + (part*256 + t)*2;
    float r0 = 0.f, r1 = 0.f;
    unsigned x = *(const unsigned*)base;
    for (int c = 0; c < NC-1; ++c) {
        unsigned xn = *(const unsigned*)(base + (int64_t)(c+1)*4096);
        unsigned o = (unsigned)f2bf(r0) | ((unsigned)f2bf(r1) << 16);
        r0 += bf2f((unsigned short)(x & 0xffffu));
        r1 += bf2f((unsigned short)(x >> 16));
        *(unsigned*)(base + (int64_t)c*4096) = o;
        x = xn;
    }
    *(unsigned*)(base + (int64_t)(NC-1)*4096) = (unsigned)f2bf(r0) | ((unsigned)f2bf(r1) << 16);
    if (part == 0 && t < DD) {
        float r = 0.f;
        float* kb = ks + (int64_t)bh*NC*DD + t;
        for (int c = 0; c < NC; ++c) { float xx = kb[(int64_t)c*DD]; kb[(int64_t)c*DD] = r; r += xx; }
    }
}

// ---------------- k3: per-chunk output, single barrier ----------------
__global__ __launch_bounds__(256) void k3(const float* __restrict__ qp, const float* __restrict__ kp,
                                          const float* __restrict__ vp,
                                          const unsigned short* __restrict__ kvt,
                                          const float* __restrict__ ks, float* __restrict__ outp)
{
    __shared__ __align__(16) unsigned short qf [DD*PAD];  // [l][d]; per-wave-private after sync; scores overlay
    __shared__ __align__(16) unsigned short kfx[80*PAD];  // [s][d]; row64=Kprefix, 65-79=0
    __shared__ __align__(16) unsigned short vtt[DD*PAD];  // v^T [m][s]
    __shared__ float zr[DD];
    const int ci = blockIdx.x;
    const int c = ci & 31, bh = ci >> 5, b = bh >> 4, h = bh & 15;
    const int t = threadIdx.x;
    const int64_t gbase = ((int64_t)(b*LL + c*DD)*HH + h)*DD;
    const unsigned short* kvg = kvt + (int64_t)ci*4096;
    const float* ksg = ks + (int64_t)ci*DD;
#pragma unroll
    for (int i = 0; i < 2; ++i) {
        int flat = t + 256*i;
        int l0 = (flat >> 4) * 2, col = (flat & 15) << 2;
        const float* gq = qp + gbase + (int64_t)l0*LSTR + col;
        const float* gk = kp + gbase + (int64_t)l0*LSTR + col;
        const float* gv = vp + gbase + (int64_t)l0*LSTR + col;
        float4 qa = *(const float4*)(gq);
        float4 qb = *(const float4*)(gq + LSTR);
        float4 ka = *(const float4*)(gk);
        float4 kb = *(const float4*)(gk + LSTR);
        float4 va = *(const float4*)(gv);
        float4 vb = *(const float4*)(gv + LSTR);
        *(ushortx4*)(qf + l0*PAD + col)      = ushortx4{ f2bf(fmap(qa.x)), f2bf(fmap(qa.y)), f2bf(fmap(qa.z)), f2bf(fmap(qa.w)) };
        *(ushortx4*)(qf + (l0+1)*PAD + col)  = ushortx4{ f2bf(fmap(qb.x)), f2bf(fmap(qb.y)), f2bf(fmap(qb.z)), f2bf(fmap(qb.w)) };
        *(ushortx4*)(kfx + l0*PAD + col)     = ushortx4{ f2bf(fmap(ka.x)), f2bf(fmap(ka.y)), f2bf(fmap(ka.z)), f2bf(fmap(ka.w)) };
        *(ushortx4*)(kfx + (l0+1)*PAD + col) = ushortx4{ f2bf(fmap(kb.x)), f2bf(fmap(kb.y)), f2bf(fmap(kb.z)), f2bf(fmap(kb.w)) };
        float vaa[4] = {va.x,va.y,va.z,va.w}, vbb[4] = {vb.x,vb.y,vb.z,vb.w};
#pragma unroll
        for (int e = 0; e < 4; ++e)
            *(ushortx2*)(vtt + (col+e)*PAD + l0) = ushortx2{ f2bf(vaa[e]), f2bf(vbb[e]) };
    }
    if (t < 135) *(ushortx8*)(kfx + 65*PAD + t*8) = ushortx8{0,0,0,0,0,0,0,0};
    if (t < DD)  kfx[64*PAD + t] = f2bf(ksg[t]);
    __syncthreads();   // the only block-wide barrier

    const int w = t >> 6, lane = t & 63, quad = lane >> 4, lr = lane & 15;
    const int l0 = 16*w;
    // A-frags of qf (own rows only -> qf becomes wave-private scratch)
    bf16x8 aq[2];
    aq[0] = ldf(qf + (l0+lr)*PAD + quad*8);
    aq[1] = ldf(qf + (l0+lr)*PAD + 32 + quad*8);
    // S^T fragments straight from global kv (16x64B segments/wave, L2-resident); issue early
    bf16x8 bs[2][4];
#pragma unroll
    for (int kk = 0; kk < 2; ++kk)
#pragma unroll
        for (int mt = 0; mt < 4; ++mt)
            bs[kk][mt] = ldf(kvg + (mt*16+lr)*DD + kk*32 + quad*8);

    // ---- GEMM1: scores = qf * kf^T; tile 4 col0 = qf . Kprefix ----
    floatx4 sc[5];
#pragma unroll
    for (int tt = 0; tt < 5; ++tt) sc[tt] = floatx4{0.f,0.f,0.f,0.f};
#pragma unroll
    for (int kk = 0; kk < 2; ++kk)
#pragma unroll
        for (int tt = 0; tt < 5; ++tt) {
            bf16x8 bb = ldf(kfx + (tt*16+lr)*PAD + kk*32 + quad*8);
            sc[tt] = __builtin_amdgcn_mfma_f32_16x16x32_bf16(aq[kk], bb, sc[tt], 0, 0, 0);
        }

    // ---- causal mask, z row-sums, overlay masked scores onto own qf rows ----
    float zp[4] = {0.f,0.f,0.f,0.f};
#pragma unroll
    for (int tt = 0; tt < 4; ++tt)
#pragma unroll
        for (int r = 0; r < 4; ++r) {
            int row = l0 + quad*4 + r;
            int col = tt*16 + lr;
            float val = (col <= row) ? sc[tt][r] : 0.f;
            zp[r] += val;
            qf[row*PAD + col] = f2bf(val);
        }
#pragma unroll
    for (int r = 0; r < 4; ++r) zp[r] += (lr == 0) ? sc[4][r] : 0.f;
#pragma unroll
    for (int m = 1; m < 16; m <<= 1)
#pragma unroll
        for (int r = 0; r < 4; ++r) zp[r] += __shfl_xor(zp[r], m, 64);
    if (lr == 0)
#pragma unroll
        for (int r = 0; r < 4; ++r) zr[l0 + quad*4 + r] = 1.f / (zp[r] + EPSF);

    // ---- GEMM2: out = Amask * v + qf * S ----
    floatx4 oa[4];
#pragma unroll
    for (int mt = 0; mt < 4; ++mt) oa[mt] = floatx4{0.f,0.f,0.f,0.f};
#pragma unroll
    for (int kk = 0; kk < 2; ++kk) {
        bf16x8 a2 = ldf(qf + (l0+lr)*PAD + kk*32 + quad*8);    // own rows (intra-wave RAW)
#pragma unroll
        for (int mt = 0; mt < 4; ++mt) {
            bf16x8 bv = ldf(vtt + (mt*16+lr)*PAD + kk*32 + quad*8);
            oa[mt] = __builtin_amdgcn_mfma_f32_16x16x32_bf16(a2, bv, oa[mt], 0, 0, 0);
        }
    }
#pragma unroll
    for (int kk = 0; kk < 2; ++kk)
#pragma unroll
        for (int mt = 0; mt < 4; ++mt)
            oa[mt] = __builtin_amdgcn_mfma_f32_16x16x32_bf16(aq[kk], bs[kk][mt], oa[mt], 0, 0, 0);
#pragma unroll
    for (int r = 0; r < 4; ++r) {
        int row = l0 + quad*4 + r;
        float rz = zr[row];
#pragma unroll
        for (int mt = 0; mt < 4; ++mt)
            outp[gbase + (int64_t)row*LSTR + mt*16 + lr] = oa[mt][r] * rz;
    }
}

extern "C" void kernel_launch(void* const* d_in, const int* in_sizes, int n_in,
                              void* d_out, int out_size, void* d_ws, size_t ws_size,
                              hipStream_t stream) {
    const float* q = (const float*)d_in[0];
    const float* k = (const float*)d_in[1];
    const float* v = (const float*)d_in[2];
    float* out = (float*)d_out;
    unsigned short* kvt = (unsigned short*)d_ws;                  // 2048*4096 bf16 = 16 MiB
    float* ks = (float*)((char*)d_ws + (size_t)2048*4096*2);      // 2048*64 fp32 = 512 KiB
    k1<<<2048, 256, 0, stream>>>(k, v, kvt, ks);
    k2<<<512,  256, 0, stream>>>(kvt, ks);
    k3<<<2048, 256, 0, stream>>>(q, k, v, kvt, ks, out);
}